// Round 9
// baseline (85.558 us; speedup 1.0000x reference)
//
#include <hip/hip_runtime.h>
#include <hip/hip_fp16.h>
#include <stdint.h>

// Local-window (5x5) KDE histogram entropy, 256 bins, bandwidth 0.1.
// sigma'((x-b)/0.1) ~ exp(-10|x-b|): only bins b0=floor(v), b0+1 carry mass
// (truncation error ~2e-3 entropy vs 6.28e-2 threshold; validated R5-R7).
//
// R9 == R8 (GPU acquisition timed out; no data to revise on).
// R8 = R7's register-resident prefix-merge, restructured for ILP + regs:
// grid gives only 3.4 waves/SIMD (1 px/lane, 3456 waves) -> latency must be
// hidden by ILP inside the wave. R7 interleaved exp-chain -> pair-loop ->
// logs -> serial T chain per value (one long spine, ~30% issue efficiency).
// Now: phase A loads (25 independent), phase B masses (25 independent exp
// chains), phase C pair-merge + logs (25 independent blocks, T in 4
// accumulators). Masses packed fp16 (k1|k0) in one dword: arrays 75->50
// VGPRs, pair body ~9 ops (3 cmp, 3 cndmask, 2 shift, v_pk_add_f16).
//   per pair j<i: d = b0_i - b0_j; addend (P1:P0) =
//     d==0 -> pk_j ; d==1 -> pk_j>>16 ; d==-1 -> pk_j<<16 ; else 0
//   T += z ln z - P ln P per slot (telescopes exactly to sum_b M ln M)
//   H = ln S - T/S.

#define W 96
#define H 96
#define TPB 256

__global__ __launch_bounds__(TPB) void entropy_kde_kernel(
    const float* __restrict__ x, float* __restrict__ out, int total)
{
    const int pid = blockIdx.x * TPB + threadIdx.x;
    if (pid >= total) return;

    const int xcol = pid % W;
    const int y    = (pid / W) % H;
    const int img  = pid / (W * H);
    const float* __restrict__ base = x + img * (H * W);

    // ---- phase A: 25 independent loads ----
    float va[25];
    #pragma unroll
    for (int i = 0; i < 25; ++i) {
        const int dy = i / 5 - 2, dx = i % 5 - 2;
        const int yy = y + dy,    xx = xcol + dx;
        va[i] = base[min(max(yy, 0), H - 1) * W + min(max(xx, 0), W - 1)];
    }

    // ---- phase B: 25 independent mass computations, packed fp16 (k1|k0) ----
    int      b0a[25];
    uint32_t pk [25];
    float S = 0.f;
    #pragma unroll
    for (int i = 0; i < 25; ++i) {
        const int dy = i / 5 - 2, dx = i % 5 - 2;
        const int yy = y + dy,    xx = xcol + dx;
        const bool ok = (yy >= 0) & (yy < H) & (xx >= 0) & (xx < W);
        const float v  = va[i];
        const int   b0 = (int)v;                    // v in [0,255) -> [0,254]
        const float f  = v - (float)b0;             // [0,1)
        const float E  = __expf(-10.f * f);         // e^{-10f}
        const float E2 = __expf(10.f * f - 10.f);   // e^{-10(1-f)}
        const float r0 = __builtin_amdgcn_rcpf(1.f + E);
        const float r1 = __builtin_amdgcn_rcpf(1.f + E2);
        const float k0 = ok ? E  * r0 * r0 : 0.f;   // mass at bin b0
        const float k1 = ok ? E2 * r1 * r1 : 0.f;   // mass at bin b0+1
        const __half2 hk = __floats2half2_rn(k0, k1);     // lo=k0, hi=k1
        const float2  kc = __half22float2(hk);            // fp16-rounded, used
        S += kc.x + kc.y;                                 // consistently in S,T
        b0a[i] = b0;
        pk[i]  = __builtin_bit_cast(uint32_t, hk);
    }

    // ---- phase C: prefix-merge + telescoping entropy terms ----
    // independent across i (arrays fixed); T split 4 ways to break the chain
    float T0 = 0.f, T1 = 0.f, T2 = 0.f, T3 = 0.f;
    #pragma unroll
    for (int i = 0; i < 25; ++i) {
        const int b0i = b0a[i];
        uint32_t Ppk = 0u;
        #pragma unroll
        for (int j = 0; j < i; ++j) {
            const int d = b0i - b0a[j];
            const uint32_t pj = pk[j];
            uint32_t t = (d == 0)  ? pj         : 0u;
            t          = (d == 1)  ? (pj >> 16) : t;
            t          = (d == -1) ? (pj << 16) : t;
            const __half2 sum = __hadd2(__builtin_bit_cast(__half2, Ppk),
                                        __builtin_bit_cast(__half2, t));
            Ppk = __builtin_bit_cast(uint32_t, sum);
        }
        const float2 P  = __half22float2(__builtin_bit_cast(__half2, Ppk));
        const float2 kc = __half22float2(__builtin_bit_cast(__half2, pk[i]));
        const float z0 = P.x + kc.x, z1 = P.y + kc.y;
        // g(z)=z ln(z+eps); g(0)=0; masked k=0 gives z==P -> term cancels
        const float t4 = z0  * __logf(z0  + 1e-10f) - P.x * __logf(P.x + 1e-10f)
                       + z1  * __logf(z1  + 1e-10f) - P.y * __logf(P.y + 1e-10f);
        if      ((i & 3) == 0) T0 += t4;
        else if ((i & 3) == 1) T1 += t4;
        else if ((i & 3) == 2) T2 += t4;
        else                   T3 += t4;
    }
    const float T  = (T0 + T1) + (T2 + T3);
    const float Sp = S + 1e-10f;
    out[pid] = __logf(Sp) - T / Sp;
}

extern "C" void kernel_launch(void* const* d_in, const int* in_sizes, int n_in,
                              void* d_out, int out_size, void* d_ws, size_t ws_size,
                              hipStream_t stream)
{
    const float* x = (const float*)d_in[0];
    float* out = (float*)d_out;
    const int total  = in_sizes[0];                    // 8*3*96*96 = 221184
    const int blocks = (total + TPB - 1) / TPB;        // 864
    entropy_kde_kernel<<<blocks, TPB, 0, stream>>>(x, out, total);
}